// Round 6
// baseline (32.229 us; speedup 1.0000x reference)
//
#include <hip/hip_runtime.h>

#define MARGIN1 0.5f
#define MARGIN2 1.0f

// Node 1: zero the scalar accumulator (1 block; kernel-boundary writeback
// makes the store visible to node 2's device-scope atomics).
__global__ void soso_zero_kernel(float* __restrict__ out) {
    if (threadIdx.x == 0) out[0] = 0.0f;
}

// Node 2: one wave (64 lanes) per 4 CONSECUTIVE groups of 3 rows (24 KB
// contiguous per wave). Lane l covers floats [4l,4l+4) and [256+4l,256+4l+4)
// of each 512-float row; all 24 float4 loads issued up front, 12 row-sums
// reduced in one 6-step butterfly (12-wide ILP). Each block contributes ONE
// device-scope atomicAdd to out (cheap: RMW at coherent point, no fences --
// round 3 showed per-block acq/rel fences cost ~180 us; round 2 showed
// same-address atomicAdd is fine). Graph ends when this kernel drains: no
// post-drain reduce node on the critical path.
__global__ __launch_bounds__(256, 4) void soso_main_kernel(
    const int* __restrict__ lab,
    const float* __restrict__ emb,
    const float* __restrict__ proto,
    float* __restrict__ out,
    int ngroups,
    float inv_count)
{
    const int lane  = threadIdx.x & 63;
    const int wid   = threadIdx.x >> 6;           // 0..3
    const int gwave = blockIdx.x * 4 + wid;
    const int g0    = gwave * 4;                  // 4 consecutive groups

    const float4 p0 = *reinterpret_cast<const float4*>(proto + 4 * lane);
    const float4 p1 = *reinterpret_cast<const float4*>(proto + 256 + 4 * lane);

    float acc = 0.0f;

    if (g0 + 3 < ngroups) {
        const float* base = emb + (size_t)g0 * 1536u;   // 12 rows * 512

        float4 e0[4][3], e1[4][3];
        int l0[4], l1[4];
#pragma unroll
        for (int gg = 0; gg < 4; ++gg) {
#pragma unroll
            for (int r = 0; r < 3; ++r) {
                const float* row = base + (gg * 3 + r) * 512;
                e0[gg][r] = *reinterpret_cast<const float4*>(row + 4 * lane);
                e1[gg][r] = *reinterpret_cast<const float4*>(row + 256 + 4 * lane);
            }
            l0[gg] = lab[3 * (g0 + gg) + 0];
            l1[gg] = lab[3 * (g0 + gg) + 1];
        }

        float s[12];
#pragma unroll
        for (int gg = 0; gg < 4; ++gg) {
#pragma unroll
            for (int r = 0; r < 3; ++r) {
                float v = 0.0f, t;
                t = p0.x - e0[gg][r].x; v = fmaf(t, t, v);
                t = p0.y - e0[gg][r].y; v = fmaf(t, t, v);
                t = p0.z - e0[gg][r].z; v = fmaf(t, t, v);
                t = p0.w - e0[gg][r].w; v = fmaf(t, t, v);
                t = p1.x - e1[gg][r].x; v = fmaf(t, t, v);
                t = p1.y - e1[gg][r].y; v = fmaf(t, t, v);
                t = p1.z - e1[gg][r].z; v = fmaf(t, t, v);
                t = p1.w - e1[gg][r].w; v = fmaf(t, t, v);
                s[gg * 3 + r] = v;
            }
        }

#pragma unroll
        for (int off = 32; off > 0; off >>= 1) {
            float t[12];
#pragma unroll
            for (int k = 0; k < 12; ++k) t[k] = __shfl_xor(s[k], off, 64);
#pragma unroll
            for (int k = 0; k < 12; ++k) s[k] += t[k];
        }

#pragma unroll
        for (int gg = 0; gg < 4; ++gg) {
            const float a = s[gg * 3 + 0], b = s[gg * 3 + 1], c = s[gg * 3 + 2];
            const float d1 = (l0[gg] == 0) ? a : (l1[gg] == 0) ? b : c;
            const float d2 = (l0[gg] == 1) ? a : (l1[gg] == 1) ? b : c;
            const float d3 = (l0[gg] == 2) ? a : (l1[gg] == 2) ? b : c;
            acc += fmaxf(d1 - d2 + MARGIN1, 0.0f)
                 + fmaxf(d2 - d3 + MARGIN1, 0.0f)
                 + fmaxf(d1 - d3 + MARGIN2, 0.0f);
        }
    } else {
        // Tail path (unused for B=49152, kept for generality).
        for (int g = g0; g < ngroups && g < g0 + 4; ++g) {
            const float* base = emb + (size_t)g * 1536u;
            float s[3];
#pragma unroll
            for (int r = 0; r < 3; ++r) {
                const float* row = base + r * 512;
                const float4 a = *reinterpret_cast<const float4*>(row + 4 * lane);
                const float4 b = *reinterpret_cast<const float4*>(row + 256 + 4 * lane);
                float v = 0.0f, t;
                t = p0.x - a.x; v = fmaf(t, t, v);
                t = p0.y - a.y; v = fmaf(t, t, v);
                t = p0.z - a.z; v = fmaf(t, t, v);
                t = p0.w - a.w; v = fmaf(t, t, v);
                t = p1.x - b.x; v = fmaf(t, t, v);
                t = p1.y - b.y; v = fmaf(t, t, v);
                t = p1.z - b.z; v = fmaf(t, t, v);
                t = p1.w - b.w; v = fmaf(t, t, v);
                s[r] = v;
            }
#pragma unroll
            for (int off = 32; off > 0; off >>= 1) {
#pragma unroll
                for (int r = 0; r < 3; ++r) s[r] += __shfl_xor(s[r], off, 64);
            }
            const int q0 = lab[3 * g + 0], q1 = lab[3 * g + 1];
            const float d1 = (q0 == 0) ? s[0] : (q1 == 0) ? s[1] : s[2];
            const float d2 = (q0 == 1) ? s[0] : (q1 == 1) ? s[1] : s[2];
            const float d3 = (q0 == 2) ? s[0] : (q1 == 2) ? s[1] : s[2];
            acc += fmaxf(d1 - d2 + MARGIN1, 0.0f)
                 + fmaxf(d2 - d3 + MARGIN1, 0.0f)
                 + fmaxf(d1 - d3 + MARGIN2, 0.0f);
        }
    }

    // Combine the block's 4 waves via LDS; ONE atomic per block, pre-scaled.
    __shared__ float smem[4];
    if (lane == 0) smem[wid] = acc;
    __syncthreads();
    if (threadIdx.x == 0) {
        const float blockSum = (smem[0] + smem[1] + smem[2] + smem[3]) * inv_count;
        atomicAdd(out, blockSum);   // device-scope, coherent across XCDs
    }
}

extern "C" void kernel_launch(void* const* d_in, const int* in_sizes, int n_in,
                              void* d_out, int out_size, void* d_ws, size_t ws_size,
                              hipStream_t stream)
{
    const int*   lab   = (const int*)d_in[0];    // true_label [B] int32
    const float* emb   = (const float*)d_in[1];  // embedding  [B,512] f32
    const float* proto = (const float*)d_in[2];  // proto      [512]   f32
    float* out = (float*)d_out;

    const int B = in_sizes[0];
    const int ngroups = B / 3;                          // 16384
    const int waves   = (ngroups + 3) / 4;              // 4 groups per wave
    const int blocks  = (waves + 3) / 4;                // 1024

    soso_zero_kernel<<<1, 64, 0, stream>>>(out);
    soso_main_kernel<<<blocks, 256, 0, stream>>>(lab, emb, proto, out,
                                                 ngroups, 1.0f / (float)ngroups);
}

// Round 7
// 22.431 us; speedup vs baseline: 1.4368x; 1.4368x over previous
//
#include <hip/hip_runtime.h>

#define MARGIN1 0.5f
#define MARGIN2 1.0f

// Kernel 1: one wave (64 lanes) per 4 CONSECUTIVE groups of 3 rows (24 KB
// contiguous per wave). Lane l covers floats [4l,4l+4) and [256+4l,256+4l+4)
// of each 512-float row; all 24 float4 loads issued up front (deep MLP), the
// 12 row-sums reduce in one 6-step butterfly (12-wide ILP). One plain partial
// store per block -- NO atomics (r2/r6: same-address atomic fan-in costs
// ~9 ns/block serialized), NO agent-scope fences (r3: ~180 us in L2 flushes).
// Kernel-boundary writeback provides cross-XCD visibility to kernel 2.
__global__ __launch_bounds__(256, 4) void soso_main_kernel(
    const int* __restrict__ lab,
    const float* __restrict__ emb,
    const float* __restrict__ proto,
    float* __restrict__ partial,
    int ngroups)
{
    const int lane  = threadIdx.x & 63;
    const int wid   = threadIdx.x >> 6;           // 0..3
    const int gwave = blockIdx.x * 4 + wid;
    const int g0    = gwave * 4;                  // 4 consecutive groups

    const float4 p0 = *reinterpret_cast<const float4*>(proto + 4 * lane);
    const float4 p1 = *reinterpret_cast<const float4*>(proto + 256 + 4 * lane);

    float acc = 0.0f;

    if (g0 + 3 < ngroups) {
        const float* base = emb + (size_t)g0 * 1536u;   // 12 rows * 512

        float4 e0[4][3], e1[4][3];
        int l0[4], l1[4];
#pragma unroll
        for (int gg = 0; gg < 4; ++gg) {
#pragma unroll
            for (int r = 0; r < 3; ++r) {
                const float* row = base + (gg * 3 + r) * 512;
                e0[gg][r] = *reinterpret_cast<const float4*>(row + 4 * lane);
                e1[gg][r] = *reinterpret_cast<const float4*>(row + 256 + 4 * lane);
            }
            l0[gg] = lab[3 * (g0 + gg) + 0];
            l1[gg] = lab[3 * (g0 + gg) + 1];
        }

        float s[12];
#pragma unroll
        for (int gg = 0; gg < 4; ++gg) {
#pragma unroll
            for (int r = 0; r < 3; ++r) {
                float v = 0.0f, t;
                t = p0.x - e0[gg][r].x; v = fmaf(t, t, v);
                t = p0.y - e0[gg][r].y; v = fmaf(t, t, v);
                t = p0.z - e0[gg][r].z; v = fmaf(t, t, v);
                t = p0.w - e0[gg][r].w; v = fmaf(t, t, v);
                t = p1.x - e1[gg][r].x; v = fmaf(t, t, v);
                t = p1.y - e1[gg][r].y; v = fmaf(t, t, v);
                t = p1.z - e1[gg][r].z; v = fmaf(t, t, v);
                t = p1.w - e1[gg][r].w; v = fmaf(t, t, v);
                s[gg * 3 + r] = v;
            }
        }

#pragma unroll
        for (int off = 32; off > 0; off >>= 1) {
            float t[12];
#pragma unroll
            for (int k = 0; k < 12; ++k) t[k] = __shfl_xor(s[k], off, 64);
#pragma unroll
            for (int k = 0; k < 12; ++k) s[k] += t[k];
        }

#pragma unroll
        for (int gg = 0; gg < 4; ++gg) {
            const float a = s[gg * 3 + 0], b = s[gg * 3 + 1], c = s[gg * 3 + 2];
            const float d1 = (l0[gg] == 0) ? a : (l1[gg] == 0) ? b : c;
            const float d2 = (l0[gg] == 1) ? a : (l1[gg] == 1) ? b : c;
            const float d3 = (l0[gg] == 2) ? a : (l1[gg] == 2) ? b : c;
            acc += fmaxf(d1 - d2 + MARGIN1, 0.0f)
                 + fmaxf(d2 - d3 + MARGIN1, 0.0f)
                 + fmaxf(d1 - d3 + MARGIN2, 0.0f);
        }
    } else {
        // Tail path (unused for B=49152, kept for generality).
        for (int g = g0; g < ngroups && g < g0 + 4; ++g) {
            const float* base = emb + (size_t)g * 1536u;
            float s[3];
#pragma unroll
            for (int r = 0; r < 3; ++r) {
                const float* row = base + r * 512;
                const float4 a = *reinterpret_cast<const float4*>(row + 4 * lane);
                const float4 b = *reinterpret_cast<const float4*>(row + 256 + 4 * lane);
                float v = 0.0f, t;
                t = p0.x - a.x; v = fmaf(t, t, v);
                t = p0.y - a.y; v = fmaf(t, t, v);
                t = p0.z - a.z; v = fmaf(t, t, v);
                t = p0.w - a.w; v = fmaf(t, t, v);
                t = p1.x - b.x; v = fmaf(t, t, v);
                t = p1.y - b.y; v = fmaf(t, t, v);
                t = p1.z - b.z; v = fmaf(t, t, v);
                t = p1.w - b.w; v = fmaf(t, t, v);
                s[r] = v;
            }
#pragma unroll
            for (int off = 32; off > 0; off >>= 1) {
#pragma unroll
                for (int r = 0; r < 3; ++r) s[r] += __shfl_xor(s[r], off, 64);
            }
            const int q0 = lab[3 * g + 0], q1 = lab[3 * g + 1];
            const float d1 = (q0 == 0) ? s[0] : (q1 == 0) ? s[1] : s[2];
            const float d2 = (q0 == 1) ? s[0] : (q1 == 1) ? s[1] : s[2];
            const float d3 = (q0 == 2) ? s[0] : (q1 == 2) ? s[1] : s[2];
            acc += fmaxf(d1 - d2 + MARGIN1, 0.0f)
                 + fmaxf(d2 - d3 + MARGIN1, 0.0f)
                 + fmaxf(d1 - d3 + MARGIN2, 0.0f);
        }
    }

    __shared__ float smem[4];
    if (lane == 0) smem[wid] = acc;
    __syncthreads();
    if (threadIdx.x == 0)
        partial[blockIdx.x] = smem[0] + smem[1] + smem[2] + smem[3];
}

// Kernel 2: deterministic single-block reduction. 1024 contiguous partials
// read as 256 x float4 (one 16B load per thread), then butterfly + LDS.
__global__ __launch_bounds__(256) void soso_reduce_kernel(
    const float* __restrict__ partial,
    float* __restrict__ out,
    float inv_count)
{
    const float4 v = reinterpret_cast<const float4*>(partial)[threadIdx.x];
    float s = (v.x + v.y) + (v.z + v.w);
#pragma unroll
    for (int off = 32; off > 0; off >>= 1)
        s += __shfl_xor(s, off, 64);
    __shared__ float smem[4];
    if ((threadIdx.x & 63) == 0) smem[threadIdx.x >> 6] = s;
    __syncthreads();
    if (threadIdx.x == 0)
        out[0] = (smem[0] + smem[1] + smem[2] + smem[3]) * inv_count;
}

extern "C" void kernel_launch(void* const* d_in, const int* in_sizes, int n_in,
                              void* d_out, int out_size, void* d_ws, size_t ws_size,
                              hipStream_t stream)
{
    const int*   lab   = (const int*)d_in[0];    // true_label [B] int32
    const float* emb   = (const float*)d_in[1];  // embedding  [B,512] f32
    const float* proto = (const float*)d_in[2];  // proto      [512]   f32
    float* out = (float*)d_out;

    const int B = in_sizes[0];
    const int ngroups = B / 3;                          // 16384
    const int waves   = (ngroups + 3) / 4;              // 4 groups per wave
    const int blocks  = (waves + 3) / 4;                // 1024

    float* partial = (float*)d_ws;                      // 1024 floats, contiguous

    soso_main_kernel<<<blocks, 256, 0, stream>>>(lab, emb, proto, partial, ngroups);
    soso_reduce_kernel<<<1, 256, 0, stream>>>(partial, out, 1.0f / (float)ngroups);
}